// Round 1
// baseline (1442.815 us; speedup 1.0000x reference)
//
#include <hip/hip_runtime.h>
#include <hip/hip_bf16.h>

typedef __attribute__((ext_vector_type(8))) short bf16x8;
typedef __attribute__((ext_vector_type(4))) float f32x4;

__device__ __forceinline__ void async16(const void* g, void* l) {
    __builtin_amdgcn_global_load_lds(
        (const __attribute__((address_space(1))) void*)g,
        (__attribute__((address_space(3))) void*)l,
        16, 0, 0);
}

__device__ __forceinline__ unsigned short f2bf(float f) {
    __hip_bfloat16 h = __float2bfloat16(f);
    union { __hip_bfloat16 h; unsigned short u; } cv;
    cv.h = h;
    return cv.u;
}

// One block per row of x: writes bf16 row, computes h[row][0:8] = 2*codes*(x@V)
__global__ __launch_bounds__(256) void prep_x(
    const float* __restrict__ x, const float* __restrict__ codes,
    const float* __restrict__ V, unsigned short* __restrict__ xb,
    float* __restrict__ h, int K) {
    const int row = blockIdx.x;
    const int t = threadIdx.x;
    const int lane = t & 63, wave = t >> 6;
    const float* xr = x + (size_t)row * K;
    unsigned short* xbr = xb + (size_t)row * K;

    float acc[8] = {0.f, 0.f, 0.f, 0.f, 0.f, 0.f, 0.f, 0.f};

    // K=4096: 4 iters, each thread handles 4 consecutive floats (coalesced float4)
    for (int it = 0; it < 4; ++it) {
        int d = (t + it * 256) * 4;
        float4 xv = *(const float4*)(xr + d);
        ushort4 pk;
        pk.x = f2bf(xv.x); pk.y = f2bf(xv.y); pk.z = f2bf(xv.z); pk.w = f2bf(xv.w);
        *(ushort4*)(xbr + d) = pk;
        const float* Vr = V + (size_t)d * 8;
        float vx[4] = {xv.x, xv.y, xv.z, xv.w};
        #pragma unroll
        for (int q = 0; q < 4; ++q) {
            float4 a = ((const float4*)(Vr + q * 8))[0];
            float4 b = ((const float4*)(Vr + q * 8))[1];
            acc[0] += vx[q] * a.x; acc[1] += vx[q] * a.y;
            acc[2] += vx[q] * a.z; acc[3] += vx[q] * a.w;
            acc[4] += vx[q] * b.x; acc[5] += vx[q] * b.y;
            acc[6] += vx[q] * b.z; acc[7] += vx[q] * b.w;
        }
    }
    // wave reduce (64 lanes)
    #pragma unroll
    for (int off = 32; off > 0; off >>= 1)
        #pragma unroll
        for (int r = 0; r < 8; ++r)
            acc[r] += __shfl_down(acc[r], off);

    __shared__ float red[4][8];
    if (lane == 0)
        #pragma unroll
        for (int r = 0; r < 8; ++r) red[wave][r] = acc[r];
    __syncthreads();
    if (t < 8) {
        float s = red[0][t] + red[1][t] + red[2][t] + red[3][t];
        h[(size_t)row * 8 + t] = 2.0f * codes[(size_t)row * 8 + t] * s;
    }
}

__global__ __launch_bounds__(256) void cast_w(
    const float* __restrict__ W, unsigned short* __restrict__ Wb, long n4) {
    long i = (long)blockIdx.x * 256 + threadIdx.x;
    if (i < n4) {
        float4 w = ((const float4*)W)[i];
        ushort4 pk;
        pk.x = f2bf(w.x); pk.y = f2bf(w.y); pk.z = f2bf(w.z); pk.w = f2bf(w.w);
        ((ushort4*)Wb)[i] = pk;
    }
}

// C[m,n] = dot(A[m,:], B[n,:]) + bias[n] + dot8(h[m,:], U[n,:])
// A: [M,K] bf16 (x), B: [N,K] bf16 (W_base), out fp32.
// 128x128 block tile, BK=64, 4 waves each computing 64x64 via 4x4 MFMA 16x16x32.
__global__ __launch_bounds__(256, 2) void gemm_bt(
    const unsigned short* __restrict__ A, const unsigned short* __restrict__ B,
    const float* __restrict__ bias, const float* __restrict__ h,
    const float* __restrict__ U, float* __restrict__ C,
    int M, int N, int K) {
    __shared__ unsigned short As[128 * 64];
    __shared__ unsigned short Bs[128 * 64];

    const int t = threadIdx.x;
    const int lane = t & 63, wave = t >> 6;
    const int wm = wave >> 1, wn = wave & 1;
    const int quad = lane >> 4, l16 = lane & 15;
    const int m0 = blockIdx.y * 128, n0 = blockIdx.x * 128;

    f32x4 acc[4][4] = {};

    for (int k0 = 0; k0 < K; k0 += 64) {
        #pragma unroll
        for (int i = 0; i < 4; ++i) {
            int off = (t + i * 256) * 8;      // element offset in the 128x64 tile
            int r = off >> 6, c = off & 63;   // tile row / col
            async16(A + (size_t)(m0 + r) * K + k0 + c, &As[off]);
            async16(B + (size_t)(n0 + r) * K + k0 + c, &Bs[off]);
        }
        __syncthreads();
        #pragma unroll
        for (int kk = 0; kk < 64; kk += 32) {
            bf16x8 af[4], bfr[4];
            #pragma unroll
            for (int i = 0; i < 4; ++i)
                af[i] = *(const bf16x8*)&As[(wm * 64 + i * 16 + l16) * 64 + kk + quad * 8];
            #pragma unroll
            for (int j = 0; j < 4; ++j)
                bfr[j] = *(const bf16x8*)&Bs[(wn * 64 + j * 16 + l16) * 64 + kk + quad * 8];
            #pragma unroll
            for (int i = 0; i < 4; ++i)
                #pragma unroll
                for (int j = 0; j < 4; ++j)
                    acc[i][j] = __builtin_amdgcn_mfma_f32_16x16x32_bf16(
                        af[i], bfr[j], acc[i][j], 0, 0, 0);
        }
        __syncthreads();
    }

    // epilogue: bias + rank-8 lora dot, fp32 store
    float ufr[4][8];
    float bs[4];
    int gcol[4];
    #pragma unroll
    for (int j = 0; j < 4; ++j) {
        int col = n0 + wn * 64 + j * 16 + l16;
        gcol[j] = col;
        const float4* Ur = (const float4*)(U + (size_t)col * 8);
        float4 u0 = Ur[0], u1 = Ur[1];
        ufr[j][0] = u0.x; ufr[j][1] = u0.y; ufr[j][2] = u0.z; ufr[j][3] = u0.w;
        ufr[j][4] = u1.x; ufr[j][5] = u1.y; ufr[j][6] = u1.z; ufr[j][7] = u1.w;
        bs[j] = bias[col];
    }
    #pragma unroll
    for (int i = 0; i < 4; ++i) {
        #pragma unroll
        for (int r = 0; r < 4; ++r) {
            int grow = m0 + wm * 64 + i * 16 + quad * 4 + r;
            const float4* hr = (const float4*)(h + (size_t)grow * 8);
            float4 h0 = hr[0], h1 = hr[1];
            float hv[8] = {h0.x, h0.y, h0.z, h0.w, h1.x, h1.y, h1.z, h1.w};
            #pragma unroll
            for (int j = 0; j < 4; ++j) {
                float v = acc[i][j][r] + bs[j];
                #pragma unroll
                for (int q = 0; q < 8; ++q) v += hv[q] * ufr[j][q];
                C[(size_t)grow * N + gcol[j]] = v;
            }
        }
    }
}

extern "C" void kernel_launch(void* const* d_in, const int* in_sizes, int n_in,
                              void* d_out, int out_size, void* d_ws, size_t ws_size,
                              hipStream_t stream) {
    const float* x     = (const float*)d_in[0];
    const float* codes = (const float*)d_in[1];
    const float* W     = (const float*)d_in[2];
    const float* b     = (const float*)d_in[3];
    const float* V     = (const float*)d_in[4];
    const float* U     = (const float*)d_in[5];
    float* out = (float*)d_out;

    const int N = in_sizes[3];                 // D_OUT = 4096
    const int K = in_sizes[2] / N;             // D_IN  = 4096
    const int M = in_sizes[0] / K;             // B*S   = 16384

    char* ws = (char*)d_ws;
    unsigned short* xb = (unsigned short*)ws;                       // M*K bf16
    unsigned short* Wb = (unsigned short*)(ws + (size_t)M * K * 2); // N*K bf16
    float* h = (float*)(ws + (size_t)M * K * 2 + (size_t)N * K * 2);// M*8 fp32

    prep_x<<<M, 256, 0, stream>>>(x, codes, V, xb, h, K);
    long n4 = (long)N * K / 4;
    cast_w<<<(int)((n4 + 255) / 256), 256, 0, stream>>>(W, Wb, n4);
    dim3 grid(N / 128, M / 128);
    gemm_bt<<<grid, 256, 0, stream>>>(xb, Wb, b, h, U, out, M, N, K);
}